// Round 1
// baseline (168.191 us; speedup 1.0000x reference)
//
#include <hip/hip_runtime.h>

// Problem constants
#define K_ENTRIES 2048
#define NROWS     32768      // B*H*W = 32*32*32
#define BR        64         // rows per block
#define CHUNK     512        // codebook entries staged per LDS chunk
#define XS        68         // padded row stride (floats) for x tile
#define ES        68         // padded row stride (floats) for e tile
#define OUT_Q_SZ  2097152    // B*C*H*W
#define N_ELEMS   2097152.0f // N*C for the loss mean

// ---------------------------------------------------------------------------
// Kernel 0: codebook squared norms -> ws[8..8+2048); zero loss accum ws[0]
// ---------------------------------------------------------------------------
__global__ void vq_norms_kernel(const float* __restrict__ cb, float* __restrict__ ws) {
    int k = blockIdx.x * blockDim.x + threadIdx.x;
    if (k == 0) ws[0] = 0.0f;
    if (k < K_ENTRIES) {
        const float4* row = (const float4*)(cb + k * 64);
        float s = 0.0f;
#pragma unroll
        for (int i = 0; i < 16; ++i) {
            float4 v = row[i];
            s += v.x * v.x + v.y * v.y + v.z * v.z + v.w * v.w;
        }
        ws[8 + k] = s;
    }
}

// ---------------------------------------------------------------------------
// Kernel 1: main fused distance/argmin/gather/scatter/loss kernel
//   grid = 512 blocks x 512 threads. Each block: 64 rows x all 2048 entries.
// ---------------------------------------------------------------------------
__global__ __launch_bounds__(512, 2) void vq_main_kernel(
    const float* __restrict__ x, const float* __restrict__ cb,
    const float* __restrict__ enorm, float* __restrict__ out_q,
    float* __restrict__ out_idx, float* __restrict__ loss_acc)
{
    __shared__ float x_s[BR * XS];        // 17,408 B
    __shared__ float e_s[CHUNK * ES];     // 139,264 B
    __shared__ int   idx_s[BR];
    __shared__ float wpart[8];

    const int tid = threadIdx.x;
    const int n0  = blockIdx.x * BR;      // first row of this block
    const int b   = n0 >> 10;             // batch index (H*W = 1024)
    const int hw0 = n0 & 1023;            // hw offset within batch
    const float* xg = x + b * 65536 + hw0;

    // ---- stage x tile: 64 rows x 64 channels (transposed store) ----
#pragma unroll
    for (int it = 0; it < 2; ++it) {
        int f  = it * 512 + tid;          // 0..1023 float4s
        int c  = f >> 4;                  // channel 0..63
        int r4 = f & 15;                  // row quad
        float4 v = *(const float4*)(xg + c * 1024 + r4 * 4);
        x_s[(r4 * 4 + 0) * XS + c] = v.x;
        x_s[(r4 * 4 + 1) * XS + c] = v.y;
        x_s[(r4 * 4 + 2) * XS + c] = v.z;
        x_s[(r4 * 4 + 3) * XS + c] = v.w;
    }

    const int rg = tid >> 6;   // row group 0..7 (== wave id); rows rg*8 .. rg*8+7
    const int eg = tid & 63;   // lane -> entry group

    float best[8];
    int   bidx[8];
#pragma unroll
    for (int i = 0; i < 8; ++i) { best[i] = 3.4e38f; bidx[i] = 0; }

#pragma unroll 1
    for (int ch = 0; ch < K_ENTRIES / CHUNK; ++ch) {
        __syncthreads();
        // ---- stage codebook chunk: 512 entries x 64 channels ----
        const float* cg = cb + ch * CHUNK * 64;
#pragma unroll
        for (int it = 0; it < 16; ++it) {
            int f     = it * 512 + tid;   // 0..8191 float4s
            int entry = f >> 4;
            int c4    = f & 15;
            float4 v = *(const float4*)(cg + entry * 64 + c4 * 4);
            *(float4*)(&e_s[entry * ES + c4 * 4]) = v;
        }
        __syncthreads();

        float acc[8][8];
#pragma unroll
        for (int i = 0; i < 8; ++i)
#pragma unroll
            for (int j = 0; j < 8; ++j) acc[i][j] = 0.0f;

#pragma unroll 2
        for (int cc = 0; cc < 64; cc += 4) {
            float4 er[8];
#pragma unroll
            for (int j = 0; j < 8; ++j)
                er[j] = *(const float4*)(&e_s[(j * 64 + eg) * ES + cc]);
#pragma unroll
            for (int i = 0; i < 8; ++i) {
                float4 xr = *(const float4*)(&x_s[(rg * 8 + i) * XS + cc]);
#pragma unroll
                for (int j = 0; j < 8; ++j)
                    acc[i][j] += xr.x * er[j].x + xr.y * er[j].y
                               + xr.z * er[j].z + xr.w * er[j].w;
            }
        }

        // ---- fold chunk into running argmin (ascending entry order) ----
#pragma unroll
        for (int j = 0; j < 8; ++j) {
            int entry = ch * CHUNK + j * 64 + eg;
            float en  = enorm[entry];
#pragma unroll
            for (int i = 0; i < 8; ++i) {
                float d = en - 2.0f * acc[i][j];
                if (d < best[i]) { best[i] = d; bidx[i] = entry; }
            }
        }
    }

    // ---- wave-wide argmin reduction (lex-min on (val, idx)) ----
#pragma unroll
    for (int i = 0; i < 8; ++i) {
        float v  = best[i];
        int   id = bidx[i];
#pragma unroll
        for (int m = 32; m >= 1; m >>= 1) {
            float ov  = __shfl_xor(v, m, 64);
            int   oid = __shfl_xor(id, m, 64);
            if (ov < v || (ov == v && oid < id)) { v = ov; id = oid; }
        }
        if (eg == 0) {
            int r = rg * 8 + i;
            idx_s[r] = id;
            out_idx[n0 + r] = (float)id;
        }
    }
    __syncthreads();

    // ---- gather quant, scatter to (B,C,H,W), accumulate loss ----
    float lsum = 0.0f;
#pragma unroll
    for (int it = 0; it < 8; ++it) {
        int e = it * 512 + tid;           // 0..4095
        int c = e >> 6;
        int r = e & 63;
        int id   = idx_s[r];
        float q  = cb[id * 64 + c];
        float xv = x_s[r * XS + c];
        float qs = xv + (q - xv);         // straight-through (matches ref arithmetic)
        out_q[b * 65536 + c * 1024 + hw0 + r] = qs;
        float df = q - xv;
        lsum += df * df;
    }
#pragma unroll
    for (int m = 32; m >= 1; m >>= 1) lsum += __shfl_xor(lsum, m, 64);
    if (eg == 0) wpart[rg] = lsum;
    __syncthreads();
    if (tid == 0) {
        float s = 0.0f;
#pragma unroll
        for (int w = 0; w < 8; ++w) s += wpart[w];
        atomicAdd(loss_acc, s);
    }
}

// ---------------------------------------------------------------------------
// Kernel 2: finalize scalar losses
// ---------------------------------------------------------------------------
__global__ void vq_finalize_kernel(const float* __restrict__ ws, float* __restrict__ out) {
    float m = ws[0] * (1.0f / N_ELEMS);
    out[OUT_Q_SZ]     = m;  // codebook_loss
    out[OUT_Q_SZ + 1] = m;  // commitment_loss (identical in forward)
}

extern "C" void kernel_launch(void* const* d_in, const int* in_sizes, int n_in,
                              void* d_out, int out_size, void* d_ws, size_t ws_size,
                              hipStream_t stream) {
    const float* x  = (const float*)d_in[0];   // (32,64,32,32)
    const float* cb = (const float*)d_in[1];   // (2048,64)
    float* out = (float*)d_out;
    float* ws  = (float*)d_ws;                 // [0]=loss accum, [8..8+2048)=norms

    vq_norms_kernel<<<8, 256, 0, stream>>>(cb, ws);
    vq_main_kernel<<<NROWS / BR, 512, 0, stream>>>(
        x, cb, ws + 8, out, out + OUT_Q_SZ + 2, ws);
    vq_finalize_kernel<<<1, 1, 0, stream>>>(ws, out);
}

// Round 2
// 83.385 us; speedup vs baseline: 2.0170x; 2.0170x over previous
//
#include <hip/hip_runtime.h>

// ---------------- problem constants ----------------
#define NROWS    32768       // B*H*W
#define KENT     2048        // codebook entries
#define OUT_Q_SZ 2097152     // B*C*H*W
#define N_ELEMS  2097152.0f
#define THR      1e-4f       // cert threshold on (m2 - m1)
#define KLO      0.001953125f // 2/1024

typedef _Float16 f16x8 __attribute__((ext_vector_type(8)));
typedef float    f32x4 __attribute__((ext_vector_type(4)));

// ws byte offsets
#define WS_LOSS  0
#define WS_CNT   4
#define WS_EN    1024                 // 2048 floats
#define WS_LIST  16384                // 32768 uints
#define WS_PM1   262144               // 32768*8 floats (1 MB)
#define WS_PIX   1310720              // 1 MB
#define WS_PM2   2359296              // 1 MB  (ends 3407872)

// ---------------------------------------------------------------------------
// K1: codebook squared norms -> en[2048]; zero loss + flag count
// ---------------------------------------------------------------------------
__global__ void vq_norms_kernel(const float* __restrict__ cb, float* __restrict__ ws) {
    int e = blockIdx.x * 256 + threadIdx.x;
    if (e == 0) { ws[0] = 0.0f; ((unsigned*)ws)[1] = 0u; }
    if (e < KENT) {
        const float4* row = (const float4*)(cb + e * 64);
        float s = 0.0f;
#pragma unroll
        for (int i = 0; i < 16; ++i) {
            float4 v = row[i];
            s += v.x * v.x + v.y * v.y + v.z * v.z + v.w * v.w;
        }
        *((float*)((char*)ws + WS_EN) + e) = s;
    }
}

// ---------------------------------------------------------------------------
// K2: main — split-f16 3-term MFMA distances + in-register top-2 argmin.
// grid = 1024 blocks (128 row-groups x 8 codebook octants) x 256 threads.
// Block: 256 rows x 256 entries-octant. Wave: 64 rows (4 N-tiles of 16).
// ---------------------------------------------------------------------------
__global__ __launch_bounds__(256, 2) void vq_main_kernel(
    const float* __restrict__ x, const float* __restrict__ cb,
    float* __restrict__ ws)
{
    __shared__ f16x8 a_hi[16 * 2 * 64];   // [tile][step][lane] 32 KB
    __shared__ f16x8 a_lo[16 * 2 * 64];   // 32 KB
    __shared__ float en_s[256];           // 1 KB

    const float*  en  = (const float*)((char*)ws + WS_EN);
    float*        pm1 = (float*)((char*)ws + WS_PM1);
    int*          pix = (int*)  ((char*)ws + WS_PIX);
    float*        pm2 = (float*)((char*)ws + WS_PM2);

    const int tid = threadIdx.x;
    const int rg  = blockIdx.x >> 3;
    const int oct = blockIdx.x & 7;

    // ---- stage codebook octant, converting fp32 -> f16 hi/lo in frag layout
#pragma unroll
    for (int u = 0; u < 8; ++u) {
        int unit = u * 256 + tid;          // (tile, step, lane)
        int tile = unit >> 7, step = (unit >> 6) & 1, ln = unit & 63;
        int e  = oct * 256 + tile * 16 + (ln & 15);
        int k0 = step * 32 + ((ln >> 4) << 3);
        float4 v0 = *(const float4*)(cb + e * 64 + k0);
        float4 v1 = *(const float4*)(cb + e * 64 + k0 + 4);
        float vv[8] = {v0.x, v0.y, v0.z, v0.w, v1.x, v1.y, v1.z, v1.w};
        f16x8 h, l;
#pragma unroll
        for (int j = 0; j < 8; ++j) {
            _Float16 hi = (_Float16)vv[j];
            float lo = (vv[j] - (float)hi) * 1024.0f;
            h[j] = hi; l[j] = (_Float16)lo;
        }
        a_hi[unit] = h; a_lo[unit] = l;
    }
    en_s[tid] = en[oct * 256 + tid];
    __syncthreads();

    // ---- x fragments for this wave's 64 rows (hi/lo), kept in registers
    const int w  = tid >> 6;
    const int ln = tid & 63;
    const int rowbase = rg * 256 + w * 64;

    f16x8 bh[4][2], bl[4][2];
#pragma unroll
    for (int nt = 0; nt < 4; ++nt) {
        int n = rowbase + nt * 16 + (ln & 15);
        const float* xp = x + ((n >> 10) << 16) + (n & 1023);
#pragma unroll
        for (int st = 0; st < 2; ++st) {
            int c0 = st * 32 + ((ln >> 4) << 3);
            f16x8 h, l;
#pragma unroll
            for (int j = 0; j < 8; ++j) {
                float f = xp[(c0 + j) << 10];
                _Float16 hi = (_Float16)f;
                float lo = (f - (float)hi) * 1024.0f;
                h[j] = hi; l[j] = (_Float16)lo;
            }
            bh[nt][st] = h; bl[nt][st] = l;
        }
    }

    float m1[4], m2[4]; int bidx[4];
#pragma unroll
    for (int nt = 0; nt < 4; ++nt) { m1[nt] = 3.4e38f; m2[nt] = 3.4e38f; bidx[nt] = 0; }
    const int ibase = oct * 256 + ((ln >> 4) << 2);

#pragma unroll 1
    for (int tile = 0; tile < 16; ++tile) {
        f16x8 ah0 = a_hi[tile * 128 + ln];
        f16x8 ah1 = a_hi[tile * 128 + 64 + ln];
        f16x8 al0 = a_lo[tile * 128 + ln];
        f16x8 al1 = a_lo[tile * 128 + 64 + ln];
        float4 en4 = *(const float4*)&en_s[tile * 16 + ((ln >> 4) << 2)];
        float env[4] = {en4.x, en4.y, en4.z, en4.w};
        int t4 = ibase + tile * 16;

#pragma unroll
        for (int nt = 0; nt < 4; ++nt) {
            f32x4 z = {0.f, 0.f, 0.f, 0.f};
            f32x4 ah = __builtin_amdgcn_mfma_f32_16x16x32_f16(ah0, bh[nt][0], z, 0, 0, 0);
            ah = __builtin_amdgcn_mfma_f32_16x16x32_f16(ah1, bh[nt][1], ah, 0, 0, 0);
            f32x4 al = __builtin_amdgcn_mfma_f32_16x16x32_f16(ah0, bl[nt][0], z, 0, 0, 0);
            al = __builtin_amdgcn_mfma_f32_16x16x32_f16(ah1, bl[nt][1], al, 0, 0, 0);
            al = __builtin_amdgcn_mfma_f32_16x16x32_f16(al0, bh[nt][0], al, 0, 0, 0);
            al = __builtin_amdgcn_mfma_f32_16x16x32_f16(al1, bh[nt][1], al, 0, 0, 0);
#pragma unroll
            for (int r = 0; r < 4; ++r) {
                float d = fmaf(ah[r], -2.0f, fmaf(al[r], -KLO, env[r]));
                bool lt = d < m1[nt];
                m2[nt] = fminf(m2[nt], fmaxf(d, m1[nt]));
                m1[nt]   = lt ? d : m1[nt];
                bidx[nt] = lt ? (t4 + r) : bidx[nt];
            }
        }
    }

    // ---- cross-lane-group merge (4 entry-quarters per row) + store partials
#pragma unroll
    for (int nt = 0; nt < 4; ++nt) {
        float v1 = m1[nt], v2 = m2[nt]; int ix = bidx[nt];
#pragma unroll
        for (int m = 16; m <= 32; m <<= 1) {
            float o1 = __shfl_xor(v1, m, 64);
            int   oi = __shfl_xor(ix, m, 64);
            float o2 = __shfl_xor(v2, m, 64);
            bool lt = (o1 < v1) || (o1 == v1 && oi < ix);
            float loser = lt ? v1 : o1;
            v1 = lt ? o1 : v1; ix = lt ? oi : ix;
            v2 = fminf(loser, fminf(v2, o2));
        }
        if (ln < 16) {
            int row = rowbase + nt * 16 + ln;
            pm1[oct * NROWS + row] = v1;
            pix[oct * NROWS + row] = ix;
            pm2[oct * NROWS + row] = v2;
        }
    }
}

// ---------------------------------------------------------------------------
// K3: merge octant partials; flag uncertain rows; gather/scatter/loss
// ---------------------------------------------------------------------------
__global__ __launch_bounds__(256) void vq_epilogue_kernel(
    const float* __restrict__ x, const float* __restrict__ cb,
    float* __restrict__ ws, float* __restrict__ out_q, float* __restrict__ out_idx)
{
    __shared__ int idx_s[64];
    __shared__ int flag_s[64];
    __shared__ float wp[4];

    const float* pm1 = (const float*)((char*)ws + WS_PM1);
    const int*   pix = (const int*)  ((char*)ws + WS_PIX);
    const float* pm2 = (const float*)((char*)ws + WS_PM2);
    unsigned*    cnt = (unsigned*)((char*)ws + WS_CNT);
    unsigned*    list = (unsigned*)((char*)ws + WS_LIST);

    const int t = threadIdx.x;
    const int base = blockIdx.x * 64;
    const int b = base >> 10, hw0 = base & 1023;

    if (t < 64) {
        int row = base + t;
        float v1 = 3.4e38f, v2 = 3.4e38f; int ix = 0;
#pragma unroll
        for (int o = 0; o < 8; ++o) {
            float o1 = pm1[o * NROWS + row];
            int   oi = pix[o * NROWS + row];
            float o2 = pm2[o * NROWS + row];
            bool lt = (o1 < v1) || (o1 == v1 && oi < ix);
            float loser = lt ? v1 : o1;
            v1 = lt ? o1 : v1; ix = lt ? oi : ix;
            v2 = fminf(loser, fminf(v2, o2));
        }
        out_idx[row] = (float)ix;
        int fl = (v2 - v1) <= THR;
        idx_s[t] = ix; flag_s[t] = fl;
        if (fl) { unsigned p = atomicAdd(cnt, 1u); list[p] = row; }
    }
    __syncthreads();

    float lsum = 0.0f;
#pragma unroll
    for (int it = 0; it < 16; ++it) {
        int e = it * 256 + t;
        int c = e >> 6, r = e & 63;
        float q  = cb[idx_s[r] * 64 + c];
        float xv = x[(b << 16) + (c << 10) + hw0 + r];
        out_q[(b << 16) + (c << 10) + hw0 + r] = xv + (q - xv);
        float df = q - xv;
        lsum += flag_s[r] ? 0.0f : df * df;
    }
#pragma unroll
    for (int m = 1; m < 64; m <<= 1) lsum += __shfl_xor(lsum, m, 64);
    if ((t & 63) == 0) wp[t >> 6] = lsum;
    __syncthreads();
    if (t == 0) atomicAdd((float*)ws, wp[0] + wp[1] + wp[2] + wp[3]);
}

// ---------------------------------------------------------------------------
// K4: exact fp32 re-scan for flagged rows (expected count ~0-3)
// ---------------------------------------------------------------------------
__global__ __launch_bounds__(256) void vq_fallback_kernel(
    const float* __restrict__ x, const float* __restrict__ cb,
    float* __restrict__ ws, float* __restrict__ out_q, float* __restrict__ out_idx)
{
    __shared__ float x_s[64];
    __shared__ float rd[256];
    __shared__ int   ri[256];

    const float* en  = (const float*)((char*)ws + WS_EN);
    const unsigned F = *(const unsigned*)((char*)ws + WS_CNT);
    const unsigned* list = (const unsigned*)((char*)ws + WS_LIST);
    const int t = threadIdx.x;

    for (unsigned li = blockIdx.x; li < F; li += gridDim.x) {
        int row = list[li];
        int b = row >> 10, hw = row & 1023;
        if (t < 64) x_s[t] = x[(b << 16) + (t << 10) + hw];
        __syncthreads();

        float best = 3.4e38f; int bi = 0;
#pragma unroll 1
        for (int i = 0; i < 8; ++i) {
            int e = i * 256 + t;
            float dot = 0.0f;
#pragma unroll
            for (int c4 = 0; c4 < 16; ++c4) {
                float4 cv = *(const float4*)(cb + e * 64 + c4 * 4);
                float4 xv = *(const float4*)&x_s[c4 * 4];
                dot += cv.x * xv.x + cv.y * xv.y + cv.z * xv.z + cv.w * xv.w;
            }
            float d = en[e] - 2.0f * dot;
            if (d < best) { best = d; bi = e; }
        }
        rd[t] = best; ri[t] = bi;
        __syncthreads();
        for (int s = 128; s > 0; s >>= 1) {
            if (t < s) {
                bool lt = (rd[t + s] < rd[t]) || (rd[t + s] == rd[t] && ri[t + s] < ri[t]);
                if (lt) { rd[t] = rd[t + s]; ri[t] = ri[t + s]; }
            }
            __syncthreads();
        }
        int ix = ri[0];
        if (t == 0) out_idx[row] = (float)ix;
        float lsum = 0.0f;
        if (t < 64) {
            float q = cb[ix * 64 + t];
            float xv = x_s[t];
            out_q[(b << 16) + (t << 10) + hw] = xv + (q - xv);
            float df = q - xv; lsum = df * df;
        }
        if (t < 64) {
#pragma unroll
            for (int m = 1; m < 64; m <<= 1) lsum += __shfl_xor(lsum, m, 64);
            if (t == 0) atomicAdd((float*)ws, lsum);
        }
        __syncthreads();
    }
}

// ---------------------------------------------------------------------------
// K5: finalize scalar losses
// ---------------------------------------------------------------------------
__global__ void vq_finalize_kernel(const float* __restrict__ ws, float* __restrict__ out) {
    float m = ws[0] * (1.0f / N_ELEMS);
    out[OUT_Q_SZ]     = m;
    out[OUT_Q_SZ + 1] = m;
}

extern "C" void kernel_launch(void* const* d_in, const int* in_sizes, int n_in,
                              void* d_out, int out_size, void* d_ws, size_t ws_size,
                              hipStream_t stream) {
    const float* x  = (const float*)d_in[0];   // (32,64,32,32)
    const float* cb = (const float*)d_in[1];   // (2048,64)
    float* out = (float*)d_out;
    float* ws  = (float*)d_ws;

    vq_norms_kernel<<<8, 256, 0, stream>>>(cb, ws);
    vq_main_kernel<<<1024, 256, 0, stream>>>(x, cb, ws);
    vq_epilogue_kernel<<<512, 256, 0, stream>>>(x, cb, ws, out, out + OUT_Q_SZ + 2);
    vq_fallback_kernel<<<64, 256, 0, stream>>>(x, cb, ws, out, out + OUT_Q_SZ + 2);
    vq_finalize_kernel<<<1, 1, 0, stream>>>(ws, out);
}

// Round 3
// 68.847 us; speedup vs baseline: 2.4430x; 1.2112x over previous
//
#include <hip/hip_runtime.h>

// ---------------- problem constants ----------------
#define NROWS    32768        // B*H*W
#define KENT     2048
#define OUT_Q_SZ 2097152      // B*C*H*W
#define N_ELEMS  2097152.0f
#define THR      1e-4f
#define KLO      0.001953125f // 2/1024

typedef _Float16 f16x8  __attribute__((ext_vector_type(8)));
typedef float    f32x16 __attribute__((ext_vector_type(16)));

// ws byte offsets
#define WS_LOSS  0
#define WS_CNT   4
#define WS_EN    1024          // 2048 f32
#define WS_LIST  16384         // 32768 u32
#define WS_CBH   262144        // 2048*64 f16 fragment-linear (256 KB)
#define WS_CBL   524288        // 256 KB

// ---------------------------------------------------------------------------
// K1: prep — convert codebook to f16 hi/lo fragments (A-layout for
// mfma_f32_32x32x16_f16), compute entry norms, zero accumulators.
// Fragment layout: f16x8 at unit = (gm*4 + ks)*64 + lane, where
//   entry = gm*32 + (lane&31), ch = ks*16 + (lane>>5)*8 + j.
// ---------------------------------------------------------------------------
__global__ __launch_bounds__(256) void vq_prep_kernel(
    const float* __restrict__ cb, float* __restrict__ ws)
{
    const int unit = blockIdx.x * 256 + threadIdx.x;   // 0..16383
    if (unit == 0) { ws[0] = 0.0f; ((unsigned*)ws)[1] = 0u; }

    const int gm = unit >> 8, ks = (unit >> 6) & 3, l = unit & 63;
    const int e  = gm * 32 + (l & 31);
    const int ch = ks * 16 + ((l >> 5) << 3);
    float4 v0 = *(const float4*)(cb + e * 64 + ch);
    float4 v1 = *(const float4*)(cb + e * 64 + ch + 4);
    float vv[8] = {v0.x, v0.y, v0.z, v0.w, v1.x, v1.y, v1.z, v1.w};
    f16x8 h, lo;
#pragma unroll
    for (int j = 0; j < 8; ++j) {
        _Float16 hi = (_Float16)vv[j];
        float r = (vv[j] - (float)hi) * 1024.0f;
        h[j] = hi; lo[j] = (_Float16)r;
    }
    *(f16x8*)((_Float16*)((char*)ws + WS_CBH) + unit * 8) = h;
    *(f16x8*)((_Float16*)((char*)ws + WS_CBL) + unit * 8) = lo;

    if (unit < KENT) {
        const float4* row = (const float4*)(cb + unit * 64);
        float s = 0.0f;
#pragma unroll
        for (int i = 0; i < 16; ++i) {
            float4 v = row[i];
            s += v.x * v.x + v.y * v.y + v.z * v.z + v.w * v.w;
        }
        *((float*)((char*)ws + WS_EN) + unit) = s;
    }
}

// ---------------------------------------------------------------------------
// K2: main — 512 blocks x 512 threads. Block owns 64 rows x all 2048 entries.
// 8 waves = 2 row-halves x 4 entry-quarters. Fused merge + epilogue.
// ---------------------------------------------------------------------------
__global__ __launch_bounds__(512, 4) void vq_main_kernel(
    const float* __restrict__ x, const float* __restrict__ cb,
    float* __restrict__ ws, float* __restrict__ out_q,
    float* __restrict__ out_idx)
{
    __shared__ float lds_x[64 * 68];       // x tile, [ch][row], stride 68
    __shared__ float mb1[64 * 4];          // per-(row, eq) partial m1
    __shared__ float mb2[64 * 4];
    __shared__ int   mbi[64 * 4];
    __shared__ int   idx_s[64];
    __shared__ int   flag_s[64];
    __shared__ float wp[8];

    const float*    en  = (const float*)((char*)ws + WS_EN);
    const _Float16* cbh = (const _Float16*)((char*)ws + WS_CBH);
    const _Float16* cbl = (const _Float16*)((char*)ws + WS_CBL);
    unsigned* cnt  = (unsigned*)((char*)ws + WS_CNT);
    unsigned* list = (unsigned*)((char*)ws + WS_LIST);

    const int tid = threadIdx.x;
    const int n0  = blockIdx.x * 64;
    const int b   = n0 >> 10;
    const int hw0 = n0 & 1023;
    const float* xg = x + b * 65536 + hw0;

    // ---- stage x tile (coalesced): thread t -> ch=t>>3, seg=t&7 ----
    {
        int c = tid >> 3, s = tid & 7;
        float4 a0 = *(const float4*)(xg + c * 1024 + s * 8);
        float4 a1 = *(const float4*)(xg + c * 1024 + s * 8 + 4);
        *(float4*)(&lds_x[c * 68 + s * 8])     = a0;
        *(float4*)(&lds_x[c * 68 + s * 8 + 4]) = a1;
    }
    __syncthreads();

    const int l  = tid & 63;
    const int wv = tid >> 6;        // 0..7
    const int rh = wv >> 2;         // row half
    const int eq = wv & 3;          // entry quarter
    const int r0 = rh * 32;

    // ---- build x B-fragments (hi/lo) in registers: 32 rows, K=64 ----
    f16x8 bh[4], bl[4];
#pragma unroll
    for (int ks = 0; ks < 4; ++ks) {
        f16x8 h, lo;
#pragma unroll
        for (int j = 0; j < 8; ++j) {
            int ch = ks * 16 + ((l >> 5) << 3) + j;
            float f = lds_x[ch * 68 + r0 + (l & 31)];
            _Float16 hi = (_Float16)f;
            float r = (f - (float)hi) * 1024.0f;
            h[j] = hi; lo[j] = (_Float16)r;
        }
        bh[ks] = h; bl[ks] = lo;
    }

    float m1 = 3.4e38f, m2 = 3.4e38f;
    int   bix = 0;
    const int lane_eoff = (l >> 5) << 2;   // 0 or 4

#pragma unroll 1
    for (int m = 0; m < 16; ++m) {
        const int gm = eq * 16 + m;
        const _Float16* ap = cbh + ((size_t)(gm * 4) * 64 + l) * 8;
        const _Float16* lp = cbl + ((size_t)(gm * 4) * 64 + l) * 8;
        f16x8 ah0 = *(const f16x8*)(ap);
        f16x8 ah1 = *(const f16x8*)(ap + 512);
        f16x8 ah2 = *(const f16x8*)(ap + 1024);
        f16x8 ah3 = *(const f16x8*)(ap + 1536);
        f16x8 al0 = *(const f16x8*)(lp);
        f16x8 al1 = *(const f16x8*)(lp + 512);
        f16x8 al2 = *(const f16x8*)(lp + 1024);
        f16x8 al3 = *(const f16x8*)(lp + 1536);

        f32x16 z = {0.f,0.f,0.f,0.f,0.f,0.f,0.f,0.f,0.f,0.f,0.f,0.f,0.f,0.f,0.f,0.f};
        f32x16 acch = __builtin_amdgcn_mfma_f32_32x32x16_f16(ah0, bh[0], z, 0, 0, 0);
        acch = __builtin_amdgcn_mfma_f32_32x32x16_f16(ah1, bh[1], acch, 0, 0, 0);
        acch = __builtin_amdgcn_mfma_f32_32x32x16_f16(ah2, bh[2], acch, 0, 0, 0);
        acch = __builtin_amdgcn_mfma_f32_32x32x16_f16(ah3, bh[3], acch, 0, 0, 0);
        f32x16 accl = __builtin_amdgcn_mfma_f32_32x32x16_f16(ah0, bl[0], z, 0, 0, 0);
        accl = __builtin_amdgcn_mfma_f32_32x32x16_f16(ah1, bl[1], accl, 0, 0, 0);
        accl = __builtin_amdgcn_mfma_f32_32x32x16_f16(ah2, bl[2], accl, 0, 0, 0);
        accl = __builtin_amdgcn_mfma_f32_32x32x16_f16(ah3, bl[3], accl, 0, 0, 0);
        accl = __builtin_amdgcn_mfma_f32_32x32x16_f16(al0, bh[0], accl, 0, 0, 0);
        accl = __builtin_amdgcn_mfma_f32_32x32x16_f16(al1, bh[1], accl, 0, 0, 0);
        accl = __builtin_amdgcn_mfma_f32_32x32x16_f16(al2, bh[2], accl, 0, 0, 0);
        accl = __builtin_amdgcn_mfma_f32_32x32x16_f16(al3, bh[3], accl, 0, 0, 0);

        const int ebase = eq * 512 + m * 32 + lane_eoff;
        const float* ep = en + ebase;
        float4 e0 = *(const float4*)(ep);
        float4 e1 = *(const float4*)(ep + 8);
        float4 e2 = *(const float4*)(ep + 16);
        float4 e3 = *(const float4*)(ep + 24);
        float ev[16] = {e0.x,e0.y,e0.z,e0.w, e1.x,e1.y,e1.z,e1.w,
                        e2.x,e2.y,e2.z,e2.w, e3.x,e3.y,e3.z,e3.w};

#pragma unroll
        for (int r = 0; r < 16; ++r) {
            float d = fmaf(acch[r], -2.0f, fmaf(accl[r], -KLO, ev[r]));
            bool lt = d < m1;
            m2 = __builtin_amdgcn_fmed3f(d, m1, m2);
            m1 = fminf(d, m1);
            bix = lt ? (ebase + ((r >> 2) << 3) + (r & 3)) : bix;
        }
    }

    // ---- merge lane-halves (entry offset 0 vs 4) ----
    {
        float o1 = __shfl_xor(m1, 32, 64);
        float o2 = __shfl_xor(m2, 32, 64);
        int   oi = __shfl_xor(bix, 32, 64);
        bool lt = (o1 < m1) || (o1 == m1 && oi < bix);
        float loser = lt ? m1 : o1;
        m1 = lt ? o1 : m1; bix = lt ? oi : bix;
        m2 = fminf(loser, fminf(m2, o2));
    }
    if (l < 32) {
        int row = r0 + l;
        mb1[row * 4 + eq] = m1;
        mb2[row * 4 + eq] = m2;
        mbi[row * 4 + eq] = bix;
    }
    __syncthreads();

    // ---- final 4-way merge per row; flag near-ties ----
    if (tid < 64) {
        float v1 = 3.4e38f, v2 = 3.4e38f; int ix = 0;
#pragma unroll
        for (int q = 0; q < 4; ++q) {
            float o1 = mb1[tid * 4 + q];
            float o2 = mb2[tid * 4 + q];
            int   oi = mbi[tid * 4 + q];
            bool lt = (o1 < v1) || (o1 == v1 && oi < ix);
            float loser = lt ? v1 : o1;
            v1 = lt ? o1 : v1; ix = lt ? oi : ix;
            v2 = fminf(loser, fminf(v2, o2));
        }
        out_idx[n0 + tid] = (float)ix;
        int fl = (v2 - v1) <= THR;
        idx_s[tid] = ix; flag_s[tid] = fl;
        if (fl) { unsigned p = atomicAdd(cnt, 1u); list[p] = n0 + tid; }
    }
    __syncthreads();

    // ---- epilogue: gather, scatter to (B,C,H,W), loss ----
    float lsum = 0.0f;
#pragma unroll
    for (int it = 0; it < 8; ++it) {
        int e = it * 512 + tid;       // 0..4095
        int c = e >> 6, r = e & 63;
        float q  = cb[idx_s[r] * 64 + c];
        float xv = lds_x[c * 68 + r];
        out_q[(b << 16) + (c << 10) + hw0 + r] = xv + (q - xv);
        float df = q - xv;
        lsum += flag_s[r] ? 0.0f : df * df;
    }
#pragma unroll
    for (int mm = 1; mm < 64; mm <<= 1) lsum += __shfl_xor(lsum, mm, 64);
    if (l == 0) wp[wv] = lsum;
    __syncthreads();
    if (tid == 0) {
        float s = 0.0f;
#pragma unroll
        for (int w = 0; w < 8; ++w) s += wp[w];
        atomicAdd((float*)ws, s);
    }
}

// ---------------------------------------------------------------------------
// K3: exact fp32 re-scan for flagged rows (expected ~0-3)
// ---------------------------------------------------------------------------
__global__ __launch_bounds__(256) void vq_fallback_kernel(
    const float* __restrict__ x, const float* __restrict__ cb,
    float* __restrict__ ws, float* __restrict__ out_q, float* __restrict__ out_idx)
{
    __shared__ float x_s[64];
    __shared__ float rd[256];
    __shared__ int   ri[256];

    const float* en = (const float*)((char*)ws + WS_EN);
    const unsigned F = *(const unsigned*)((char*)ws + WS_CNT);
    const unsigned* list = (const unsigned*)((char*)ws + WS_LIST);
    const int t = threadIdx.x;

    for (unsigned li = blockIdx.x; li < F; li += gridDim.x) {
        int row = list[li];
        int b = row >> 10, hw = row & 1023;
        if (t < 64) x_s[t] = x[(b << 16) + (t << 10) + hw];
        __syncthreads();

        float best = 3.4e38f; int bi = 0;
#pragma unroll 1
        for (int i = 0; i < 8; ++i) {
            int e = i * 256 + t;
            float dot = 0.0f;
#pragma unroll
            for (int c4 = 0; c4 < 16; ++c4) {
                float4 cv = *(const float4*)(cb + e * 64 + c4 * 4);
                float4 xv = *(const float4*)&x_s[c4 * 4];
                dot += cv.x * xv.x + cv.y * xv.y + cv.z * xv.z + cv.w * xv.w;
            }
            float d = en[e] - 2.0f * dot;
            if (d < best) { best = d; bi = e; }
        }
        rd[t] = best; ri[t] = bi;
        __syncthreads();
        for (int s = 128; s > 0; s >>= 1) {
            if (t < s) {
                bool lt = (rd[t + s] < rd[t]) || (rd[t + s] == rd[t] && ri[t + s] < ri[t]);
                if (lt) { rd[t] = rd[t + s]; ri[t] = ri[t + s]; }
            }
            __syncthreads();
        }
        int ix = ri[0];
        if (t == 0) out_idx[row] = (float)ix;
        if (t < 64) {
            float q = cb[ix * 64 + t];
            float xv = x_s[t];
            out_q[(b << 16) + (t << 10) + hw] = xv + (q - xv);
            float df = q - xv;
            float lsum = df * df;
#pragma unroll
            for (int mm = 1; mm < 64; mm <<= 1) lsum += __shfl_xor(lsum, mm, 64);
            if (t == 0) atomicAdd((float*)ws, lsum);
        }
        __syncthreads();
    }
}

// ---------------------------------------------------------------------------
// K4: finalize scalar losses
// ---------------------------------------------------------------------------
__global__ void vq_finalize_kernel(const float* __restrict__ ws, float* __restrict__ out) {
    float m = ws[0] * (1.0f / N_ELEMS);
    out[OUT_Q_SZ]     = m;
    out[OUT_Q_SZ + 1] = m;
}

extern "C" void kernel_launch(void* const* d_in, const int* in_sizes, int n_in,
                              void* d_out, int out_size, void* d_ws, size_t ws_size,
                              hipStream_t stream) {
    const float* x  = (const float*)d_in[0];   // (32,64,32,32)
    const float* cb = (const float*)d_in[1];   // (2048,64)
    float* out = (float*)d_out;
    float* ws  = (float*)d_ws;

    vq_prep_kernel<<<64, 256, 0, stream>>>(cb, ws);
    vq_main_kernel<<<512, 512, 0, stream>>>(x, cb, ws, out, out + OUT_Q_SZ + 2);
    vq_fallback_kernel<<<64, 256, 0, stream>>>(x, cb, ws, out, out + OUT_Q_SZ + 2);
    vq_finalize_kernel<<<1, 1, 0, stream>>>(ws, out);
}

// Round 6
// 68.096 us; speedup vs baseline: 2.4699x; 1.0110x over previous
//
#include <hip/hip_runtime.h>

// ---------------- problem constants ----------------
#define NROWS    32768
#define KENT     2048
#define OUT_Q_SZ 2097152
#define N_ELEMS  2097152.0f
#define THRG     1e-4f         // cert threshold in g-units (= 2e-4 on d)
#define KLO      0.0009765625f // 1/1024  (g = aA + cA/1024 — NOT 2/1024)

typedef _Float16 f16x8  __attribute__((ext_vector_type(8)));
typedef float    f32x16 __attribute__((ext_vector_type(16)));

// ws byte offsets
#define WS_EN    1024      // raw ||e||^2, 2048 f32
#define WS_ENH   9216      // permuted -||e||^2/2 in C-fragment order
#define WS_LIST  20480     // flagged-row list, 32768 u32
#define WS_CBH   262144    // hi f16 fragments (256 KB)
#define WS_CBL   524288    // lo f16 fragments (256 KB)

// ---------------------------------------------------------------------------
// K1: prep — codebook -> f16 hi/lo fragments (A-layout for mfma 32x32x16),
// entry norms (raw + permuted-negated-half), zero accumulators.
// ---------------------------------------------------------------------------
__global__ __launch_bounds__(256) void vq_prep_kernel(
    const float* __restrict__ cb, float* __restrict__ ws)
{
    const int unit = blockIdx.x * 256 + threadIdx.x;   // 0..16383
    if (unit == 0) { ws[0] = 0.0f; ((unsigned*)ws)[1] = 0u; }

    const int gm = unit >> 8, ks = (unit >> 6) & 3, l = unit & 63;
    const int e  = gm * 32 + (l & 31);
    const int ch = ks * 16 + ((l >> 5) << 3);
    float4 v0 = *(const float4*)(cb + e * 64 + ch);
    float4 v1 = *(const float4*)(cb + e * 64 + ch + 4);
    float vv[8] = {v0.x,v0.y,v0.z,v0.w, v1.x,v1.y,v1.z,v1.w};
    f16x8 h, lo;
#pragma unroll
    for (int j = 0; j < 8; ++j) {
        _Float16 hi = (_Float16)vv[j];
        float r = (vv[j] - (float)hi) * 1024.0f;
        h[j] = hi; lo[j] = (_Float16)r;
    }
    *(f16x8*)((_Float16*)((char*)ws + WS_CBH) + (size_t)unit * 8) = h;
    *(f16x8*)((_Float16*)((char*)ws + WS_CBL) + (size_t)unit * 8) = lo;

    if (unit < KENT) {
        const float4* row = (const float4*)(cb + unit * 64);
        float s = 0.0f;
#pragma unroll
        for (int i = 0; i < 16; ++i) {
            float4 v = row[i];
            s += v.x * v.x + v.y * v.y + v.z * v.z + v.w * v.w;
        }
        *((float*)((char*)ws + WS_EN) + unit) = s;
        // permuted -||e||^2/2 so that enh[base + half*16 + reg] pairs with
        // C-row = (reg&3) + 8*(reg>>2) + 4*half
        int ein = unit & 31;
        int half = (ein >> 2) & 1;
        int r = (ein & 3) + ((ein >> 3) << 2);
        *((float*)((char*)ws + WS_ENH) + (unit & ~31) + half * 16 + r) = -0.5f * s;
    }
}

// ---------------------------------------------------------------------------
// K2: main — 256 blocks x 512 threads. Block owns 128 rows x all 2048
// entries. 8 waves = 2 row-groups x 4 entry-quarters; each wave does
// 24 MFMA/iter in 4 independent chains. enh baked into accumulator init.
// Fused merge + flag + epilogue.
// ---------------------------------------------------------------------------
__global__ __launch_bounds__(512, 2) void vq_main_kernel(
    const float* __restrict__ x, const float* __restrict__ cb,
    float* __restrict__ ws, float* __restrict__ out_q,
    float* __restrict__ out_idx)
{
    __shared__ float lds_x[64 * 132];        // [ch][row0..127], stride 132
    __shared__ float mb1[128 * 4], mb2[128 * 4];
    __shared__ int   mbi[128 * 4];
    __shared__ int   idx_s[128], flag_s[128];
    __shared__ float wp[8];

    const float*    enhp = (const float*)((char*)ws + WS_ENH);
    const _Float16* cbh  = (const _Float16*)((char*)ws + WS_CBH);
    const _Float16* cbl  = (const _Float16*)((char*)ws + WS_CBL);
    unsigned* cnt  = (unsigned*)ws + 1;
    unsigned* list = (unsigned*)((char*)ws + WS_LIST);

    const int tid = threadIdx.x, bid = blockIdx.x;
    const int n0  = bid * 128;
    const int b   = n0 >> 10;
    const int hw0 = n0 & 1023;
    const float* xg = x + b * 65536 + hw0;

    // ---- stage x tile: 128 rows x 64 ch ----
#pragma unroll
    for (int it = 0; it < 4; ++it) {
        int f = it * 512 + tid;            // 0..2047 float4 units
        int c = f >> 5, seg = f & 31;
        float4 v = *(const float4*)(xg + c * 1024 + seg * 4);
        *(float4*)(&lds_x[c * 132 + seg * 4]) = v;
    }
    __syncthreads();

    const int l   = tid & 63;
    const int wv  = tid >> 6;
    const int rgp = wv >> 2;     // rows rgp*64 .. +63
    const int eq  = wv & 3;      // entry quarter
    const int r0  = rgp * 64;

    // B-fragments (hi/lo) for two 32-row sub-tiles
    f16x8 bh[2][4], bl[2][4];
#pragma unroll
    for (int s = 0; s < 2; ++s)
#pragma unroll
        for (int ks = 0; ks < 4; ++ks) {
            f16x8 h, lo;
#pragma unroll
            for (int j = 0; j < 8; ++j) {
                int ch = ks * 16 + ((l >> 5) << 3) + j;
                float f = lds_x[ch * 132 + r0 + s * 32 + (l & 31)];
                _Float16 hi = (_Float16)f;
                float r = (f - (float)hi) * 1024.0f;
                h[j] = hi; lo[j] = (_Float16)r;
            }
            bh[s][ks] = h; bl[s][ks] = lo;
        }

    // 4 independent argmax trackers per sub-tile
    float m1[2][4], m2[2][4]; int bx[2][4];
#pragma unroll
    for (int s = 0; s < 2; ++s)
#pragma unroll
        for (int t = 0; t < 4; ++t) { m1[s][t] = -3.4e38f; m2[s][t] = -3.4e38f; bx[s][t] = 0; }

#pragma unroll 2
    for (int m = 0; m < 16; ++m) {
        const _Float16* ap = cbh + ((size_t)((eq * 16 + m) * 4) * 64 + l) * 8;
        const _Float16* lp = cbl + ((size_t)((eq * 16 + m) * 4) * 64 + l) * 8;
        f16x8 ah0 = *(const f16x8*)(ap);
        f16x8 ah1 = *(const f16x8*)(ap + 512);
        f16x8 ah2 = *(const f16x8*)(ap + 1024);
        f16x8 ah3 = *(const f16x8*)(ap + 1536);
        f16x8 al0 = *(const f16x8*)(lp);
        f16x8 al1 = *(const f16x8*)(lp + 512);
        f16x8 al2 = *(const f16x8*)(lp + 1024);
        f16x8 al3 = *(const f16x8*)(lp + 1536);

        f32x16 aA;
        {
            const float4* ep4 = (const float4*)(enhp + eq * 512 + m * 32 + ((l >> 5) << 4));
            float4 q0 = ep4[0], q1 = ep4[1], q2 = ep4[2], q3 = ep4[3];
            aA[0]=q0.x; aA[1]=q0.y; aA[2]=q0.z; aA[3]=q0.w;
            aA[4]=q1.x; aA[5]=q1.y; aA[6]=q1.z; aA[7]=q1.w;
            aA[8]=q2.x; aA[9]=q2.y; aA[10]=q2.z; aA[11]=q2.w;
            aA[12]=q3.x; aA[13]=q3.y; aA[14]=q3.z; aA[15]=q3.w;
        }
        f32x16 aB = aA;
        f32x16 cA = {0.f,0.f,0.f,0.f,0.f,0.f,0.f,0.f,0.f,0.f,0.f,0.f,0.f,0.f,0.f,0.f};
        f32x16 cB = cA;

        aA = __builtin_amdgcn_mfma_f32_32x32x16_f16(ah0, bh[0][0], aA, 0, 0, 0);
        aB = __builtin_amdgcn_mfma_f32_32x32x16_f16(ah0, bh[1][0], aB, 0, 0, 0);
        cA = __builtin_amdgcn_mfma_f32_32x32x16_f16(ah0, bl[0][0], cA, 0, 0, 0);
        cB = __builtin_amdgcn_mfma_f32_32x32x16_f16(ah0, bl[1][0], cB, 0, 0, 0);
        aA = __builtin_amdgcn_mfma_f32_32x32x16_f16(ah1, bh[0][1], aA, 0, 0, 0);
        aB = __builtin_amdgcn_mfma_f32_32x32x16_f16(ah1, bh[1][1], aB, 0, 0, 0);
        cA = __builtin_amdgcn_mfma_f32_32x32x16_f16(ah1, bl[0][1], cA, 0, 0, 0);
        cB = __builtin_amdgcn_mfma_f32_32x32x16_f16(ah1, bl[1][1], cB, 0, 0, 0);
        aA = __builtin_amdgcn_mfma_f32_32x32x16_f16(ah2, bh[0][2], aA, 0, 0, 0);
        aB = __builtin_amdgcn_mfma_f32_32x32x16_f16(ah2, bh[1][2], aB, 0, 0, 0);
        cA = __builtin_amdgcn_mfma_f32_32x32x16_f16(ah2, bl[0][2], cA, 0, 0, 0);
        cB = __builtin_amdgcn_mfma_f32_32x32x16_f16(ah2, bl[1][2], cB, 0, 0, 0);
        aA = __builtin_amdgcn_mfma_f32_32x32x16_f16(ah3, bh[0][3], aA, 0, 0, 0);
        aB = __builtin_amdgcn_mfma_f32_32x32x16_f16(ah3, bh[1][3], aB, 0, 0, 0);
        cA = __builtin_amdgcn_mfma_f32_32x32x16_f16(ah3, bl[0][3], cA, 0, 0, 0);
        cB = __builtin_amdgcn_mfma_f32_32x32x16_f16(ah3, bl[1][3], cB, 0, 0, 0);
        cA = __builtin_amdgcn_mfma_f32_32x32x16_f16(al0, bh[0][0], cA, 0, 0, 0);
        cB = __builtin_amdgcn_mfma_f32_32x32x16_f16(al0, bh[1][0], cB, 0, 0, 0);
        cA = __builtin_amdgcn_mfma_f32_32x32x16_f16(al1, bh[0][1], cA, 0, 0, 0);
        cB = __builtin_amdgcn_mfma_f32_32x32x16_f16(al1, bh[1][1], cB, 0, 0, 0);
        cA = __builtin_amdgcn_mfma_f32_32x32x16_f16(al2, bh[0][2], cA, 0, 0, 0);
        cB = __builtin_amdgcn_mfma_f32_32x32x16_f16(al2, bh[1][2], cB, 0, 0, 0);
        cA = __builtin_amdgcn_mfma_f32_32x32x16_f16(al3, bh[0][3], cA, 0, 0, 0);
        cB = __builtin_amdgcn_mfma_f32_32x32x16_f16(al3, bh[1][3], cB, 0, 0, 0);

        const int ebl = eq * 512 + m * 32 + ((l >> 5) << 2);
#pragma unroll
        for (int r = 0; r < 16; ++r) {
            int t = r >> 2;
            int ent = ebl + ((r >> 2) << 3) + (r & 3);
            float gA = fmaf(cA[r], KLO, aA[r]);
            bool  tA = gA > m1[0][t];
            m2[0][t] = __builtin_amdgcn_fmed3f(gA, m1[0][t], m2[0][t]);
            m1[0][t] = fmaxf(gA, m1[0][t]);
            bx[0][t] = tA ? ent : bx[0][t];
            float gB = fmaf(cB[r], KLO, aB[r]);
            bool  tB = gB > m1[1][t];
            m2[1][t] = __builtin_amdgcn_fmed3f(gB, m1[1][t], m2[1][t]);
            m1[1][t] = fmaxf(gB, m1[1][t]);
            bx[1][t] = tB ? ent : bx[1][t];
        }
    }

    // ---- merge trackers + lane-halves; store per-(row, eq) partials ----
#pragma unroll
    for (int s = 0; s < 2; ++s) {
        float v1 = m1[s][0], v2 = m2[s][0]; int ix = bx[s][0];
#pragma unroll
        for (int t = 1; t < 4; ++t) {
            bool gt = (m1[s][t] > v1) || (m1[s][t] == v1 && bx[s][t] < ix);
            float loser = gt ? v1 : m1[s][t];
            v1 = gt ? m1[s][t] : v1;
            ix = gt ? bx[s][t] : ix;
            v2 = fmaxf(loser, fmaxf(v2, m2[s][t]));
        }
        float o1 = __shfl_xor(v1, 32, 64);
        float o2 = __shfl_xor(v2, 32, 64);
        int   oi = __shfl_xor(ix, 32, 64);
        bool gt = (o1 > v1) || (o1 == v1 && oi < ix);
        float loser = gt ? v1 : o1;
        v1 = gt ? o1 : v1; ix = gt ? oi : ix;
        v2 = fmaxf(loser, fmaxf(v2, o2));
        if (l < 32) {
            int row = r0 + s * 32 + l;
            mb1[row * 4 + eq] = v1;
            mb2[row * 4 + eq] = v2;
            mbi[row * 4 + eq] = ix;
        }
    }
    __syncthreads();

    // ---- final 4-way merge per row; flag near-ties ----
    if (tid < 128) {
        float v1 = -3.4e38f, v2 = -3.4e38f; int ix = 0;
#pragma unroll
        for (int q = 0; q < 4; ++q) {
            float o1 = mb1[tid * 4 + q];
            float o2 = mb2[tid * 4 + q];
            int   oi = mbi[tid * 4 + q];
            bool gt = (o1 > v1) || (o1 == v1 && oi < ix);
            float loser = gt ? v1 : o1;
            v1 = gt ? o1 : v1; ix = gt ? oi : ix;
            v2 = fmaxf(loser, fmaxf(v2, o2));
        }
        out_idx[n0 + tid] = (float)ix;
        int fl = (v1 - v2) <= THRG;
        idx_s[tid] = ix; flag_s[tid] = fl;
        if (fl) { unsigned p = atomicAdd(cnt, 1u); list[p] = n0 + tid; }
    }
    __syncthreads();

    // ---- epilogue: gather, scatter, loss ----
    float lsum = 0.0f;
#pragma unroll
    for (int it = 0; it < 16; ++it) {
        int e = it * 512 + tid;     // 0..8191
        int c = e >> 7, r = e & 127;
        float q  = cb[idx_s[r] * 64 + c];
        float xv = lds_x[c * 132 + r];
        out_q[(b << 16) + (c << 10) + hw0 + r] = xv + (q - xv);
        float df = q - xv;
        lsum += flag_s[r] ? 0.0f : df * df;
    }
#pragma unroll
    for (int mm = 1; mm < 64; mm <<= 1) lsum += __shfl_xor(lsum, mm, 64);
    if (l == 0) wp[wv] = lsum;
    __syncthreads();
    if (tid == 0) {
        float s = 0.0f;
#pragma unroll
        for (int w = 0; w < 8; ++w) s += wp[w];
        atomicAdd(ws, s);
    }
}

// ---------------------------------------------------------------------------
// K3: exact fp32 re-scan for flagged rows (expected ~5-20)
// ---------------------------------------------------------------------------
__global__ __launch_bounds__(256) void vq_fallback_kernel(
    const float* __restrict__ x, const float* __restrict__ cb,
    float* __restrict__ ws, float* __restrict__ out_q, float* __restrict__ out_idx)
{
    __shared__ float x_s[64];
    __shared__ float rd[256];
    __shared__ int   ri[256];

    const float* en = (const float*)((char*)ws + WS_EN);
    const unsigned F = *(const unsigned*)((char*)ws + 4);
    const unsigned* list = (const unsigned*)((char*)ws + WS_LIST);
    const int t = threadIdx.x;

    for (unsigned li = blockIdx.x; li < F; li += gridDim.x) {
        int row = list[li];
        int b = row >> 10, hw = row & 1023;
        if (t < 64) x_s[t] = x[(b << 16) + (t << 10) + hw];
        __syncthreads();

        float best = 3.4e38f; int bi = 0;
#pragma unroll 1
        for (int i = 0; i < 8; ++i) {
            int e = i * 256 + t;
            float dot = 0.0f;
#pragma unroll
            for (int c4 = 0; c4 < 16; ++c4) {
                float4 cv = *(const float4*)(cb + e * 64 + c4 * 4);
                float4 xv = *(const float4*)&x_s[c4 * 4];
                dot += cv.x * xv.x + cv.y * xv.y + cv.z * xv.z + cv.w * xv.w;
            }
            float d = en[e] - 2.0f * dot;
            if (d < best) { best = d; bi = e; }
        }
        rd[t] = best; ri[t] = bi;
        __syncthreads();
        for (int s = 128; s > 0; s >>= 1) {
            if (t < s) {
                bool lt = (rd[t + s] < rd[t]) ||
                          (rd[t + s] == rd[t] && ri[t + s] < ri[t]);
                if (lt) { rd[t] = rd[t + s]; ri[t] = ri[t + s]; }
            }
            __syncthreads();
        }
        int ix = ri[0];
        if (t == 0) out_idx[row] = (float)ix;
        if (t < 64) {
            float q = cb[ix * 64 + t];
            float xv = x_s[t];
            out_q[(b << 16) + (t << 10) + hw] = xv + (q - xv);
            float df = q - xv;
            float ls = df * df;
#pragma unroll
            for (int mm = 1; mm < 64; mm <<= 1) ls += __shfl_xor(ls, mm, 64);
            if (t == 0) atomicAdd(ws, ls);
        }
        __syncthreads();
    }
}

// ---------------------------------------------------------------------------
// K4: finalize scalar losses
// ---------------------------------------------------------------------------
__global__ void vq_finalize_kernel(const float* __restrict__ ws, float* __restrict__ out) {
    float m = ws[0] * (1.0f / N_ELEMS);
    out[OUT_Q_SZ]     = m;
    out[OUT_Q_SZ + 1] = m;
}

extern "C" void kernel_launch(void* const* d_in, const int* in_sizes, int n_in,
                              void* d_out, int out_size, void* d_ws, size_t ws_size,
                              hipStream_t stream) {
    const float* x  = (const float*)d_in[0];   // (32,64,32,32)
    const float* cb = (const float*)d_in[1];   // (2048,64)
    float* out  = (float*)d_out;
    float* ws   = (float*)d_ws;
    float* oidx = out + OUT_Q_SZ + 2;

    vq_prep_kernel<<<64, 256, 0, stream>>>(cb, ws);
    vq_main_kernel<<<256, 512, 0, stream>>>(x, cb, ws, out, oidx);
    vq_fallback_kernel<<<64, 256, 0, stream>>>(x, cb, ws, out, oidx);
    vq_finalize_kernel<<<1, 1, 0, stream>>>(ws, out);
}